// Round 1
// baseline (7473.228 us; speedup 1.0000x reference)
//
#include <hip/hip_runtime.h>
#include <stdint.h>

typedef unsigned short us;
typedef __attribute__((ext_vector_type(8))) short bf16x8;
typedef __attribute__((ext_vector_type(4))) float f32x4;

#define DI __device__ __forceinline__

constexpr int LS = 48, LT = 48, NB = 64, E = 512, H = 512, G = 2048, V = 32000;
constexpr int TD = LT - 1;       // 47 decoder steps
constexpr int MENC = LS * NB;    // 3072
constexpr int MDEC = TD * NB;    // 3008
constexpr int NCB = V / 64;      // 500 column blocks for logits stats

DI float bf2f(us u) { union { unsigned int i; float f; } c; c.i = ((unsigned int)u) << 16; return c.f; }
DI us f2bf(float f) { union { float f; unsigned int i; } c; c.f = f; return (us)((c.i + 0x7fffu + ((c.i >> 16) & 1u)) >> 16); }
DI float sigm(float x) { return 1.f / (1.f + __expf(-x)); }
DI float tanh_(float x) { x = fminf(15.f, fmaxf(-15.f, x)); float e = __expf(2.f * x); return (e - 1.f) / (e + 1.f); }

// ---------------- utility kernels ----------------
__global__ __launch_bounds__(256) void zero_k(float* p, int n) {
    int i = blockIdx.x * 256 + threadIdx.x;
    if (i < n) p[i] = 0.f;
}

// dst[r*cols+c] = bf16(src[r*lds + coff + c])
__global__ __launch_bounds__(256) void conv_bf16(const float* __restrict__ src, int lds, int coff,
                                                 us* __restrict__ dst, int rows, int cols) {
    int i = blockIdx.x * 256 + threadIdx.x;
    if (i >= rows * cols) return;
    int r = i / cols, c = i % cols;
    dst[i] = f2bf(src[(size_t)r * lds + coff + c]);
}

// row r of dst = emb[idx[r]] (E=512 cols), converted to bf16
__global__ __launch_bounds__(256) void gather_bf16(const int* __restrict__ idx, const float* __restrict__ emb,
                                                   us* __restrict__ dst) {
    int r = blockIdx.x;
    int id = idx[r];
    const float* s = emb + (size_t)id * E;
    us* d = dst + (size_t)r * E;
    for (int c = threadIdx.x; c < E; c += 256) d[c] = f2bf(s[c]);
}

// Wcomb[j][0:512] = dec_Wih[j][512:1024]; Wcomb[j][512:1024] = dec_Whh[j][:]
__global__ __launch_bounds__(256) void pack_wcomb(const float* __restrict__ Wih, const float* __restrict__ Whh,
                                                  float* __restrict__ Wc) {
    int i = blockIdx.x * 256 + threadIdx.x;  // 2048*1024
    int j = i >> 10, c = i & 1023;
    Wc[i] = (c < 512) ? Wih[(size_t)j * 1024 + 512 + c] : Whh[(size_t)j * 512 + (c - 512)];
}

// ---------------- bf16 MFMA GEMM: C[M][N] = A[M][K] @ W[N][K]^T (+bias) ----------------
// grid = (N/64, M/64), block 256 (4 waves). EPI==1: bf16 store. EPI==2: logsumexp stats per 64-col block.
template <int EPI>
__global__ __launch_bounds__(256) void gemm16(const us* __restrict__ A, int lda,
                                              const us* __restrict__ W, int ldw,
                                              const float* __restrict__ b1, const float* __restrict__ b2,
                                              void* __restrict__ outp, int ldc, int K, int Mrows) {
    __shared__ us As[64][40];  // +8 pad: row stride 80B (16B-aligned, 2-way bank alias = free)
    __shared__ us Ws[64][40];
    const int tid = threadIdx.x;
    const int m0 = blockIdx.y << 6, n0 = blockIdx.x << 6;
    const int srow = tid >> 2, sk = (tid & 3) << 3;
    const int l = tid & 63, w = tid >> 6;
    const int la = l & 15, lb = l >> 4;
    f32x4 acc[4] = {};
    const us* Aptr = A + (size_t)(m0 + srow) * lda + sk;
    const us* Wptr = W + (size_t)(n0 + srow) * ldw + sk;
    for (int k0 = 0; k0 < K; k0 += 32) {
        *(uint4*)&As[srow][sk] = *(const uint4*)(Aptr + k0);
        *(uint4*)&Ws[srow][sk] = *(const uint4*)(Wptr + k0);
        __syncthreads();
        bf16x8 af = *(bf16x8*)&As[(w << 4) + la][lb << 3];
#pragma unroll
        for (int c = 0; c < 4; c++) {
            bf16x8 bw = *(bf16x8*)&Ws[(c << 4) + la][lb << 3];
            acc[c] = __builtin_amdgcn_mfma_f32_16x16x32_bf16(af, bw, acc[c], 0, 0, 0);
        }
        __syncthreads();
    }
    if (EPI == 1) {
        us* O = (us*)outp;
#pragma unroll
        for (int c = 0; c < 4; c++) {
            int col = n0 + (c << 4) + la;
            float badd = (b1 ? b1[col] : 0.f) + (b2 ? b2[col] : 0.f);
#pragma unroll
            for (int r = 0; r < 4; r++) {
                int row = m0 + (w << 4) + (lb << 2) + r;
                O[(size_t)row * ldc + col] = f2bf(acc[c][r] + badd);
            }
        }
    } else {  // EPI == 2: per-row (max, sumexp) over this 64-col block -> stats[cb][row][2]
        float* S = (float*)outp;
        float x[4][4];
#pragma unroll
        for (int c = 0; c < 4; c++) {
            int col = n0 + (c << 4) + la;
            float badd = b1[col];
#pragma unroll
            for (int r = 0; r < 4; r++) x[c][r] = acc[c][r] + badd;
        }
#pragma unroll
        for (int r = 0; r < 4; r++) {
            float lm = fmaxf(fmaxf(x[0][r], x[1][r]), fmaxf(x[2][r], x[3][r]));
#pragma unroll
            for (int mk = 1; mk < 16; mk <<= 1) lm = fmaxf(lm, __shfl_xor(lm, mk));
            float ls = __expf(x[0][r] - lm) + __expf(x[1][r] - lm) + __expf(x[2][r] - lm) + __expf(x[3][r] - lm);
#pragma unroll
            for (int mk = 1; mk < 16; mk <<= 1) ls += __shfl_xor(ls, mk);
            if (la == 0) {
                int row = m0 + (w << 4) + (lb << 2) + r;
                size_t o = ((size_t)blockIdx.x * Mrows + row) * 2;
                S[o] = lm;
                S[o + 1] = ls;
            }
        }
    }
}

// ---------------- encoder LSTM step (both directions), fp32 ----------------
// grid (32 jtiles, 4 btiles, 2 dirs), block 256 = 16b x 16j. One cell per thread.
__global__ __launch_bounds__(256) void enc_step(const us* __restrict__ gxf, const us* __restrict__ gxb,
                                                const float* __restrict__ Whhf, const float* __restrict__ Whhb,
                                                const float* __restrict__ hinf, const float* __restrict__ hinb,
                                                float* __restrict__ houtf, float* __restrict__ houtb,
                                                float* __restrict__ cf, float* __restrict__ cb_,
                                                float* __restrict__ hs, us* __restrict__ hs_bf, int s) {
    const int dir = blockIdx.z;
    const us* gx = dir ? gxb : gxf;
    const float* Whh = dir ? Whhb : Whhf;
    const float* hin = dir ? hinb : hinf;
    float* hout = dir ? houtb : houtf;
    float* cst = dir ? cb_ : cf;
    const int lrow = dir ? (LS - 1 - s) : s;
    __shared__ float hls[16][516];
    const int tid = threadIdx.x;
    const int bl = tid & 15, jl = tid >> 4;
    const int b0 = blockIdx.y * 16;
    const int j = blockIdx.x * 16 + jl;
    for (int idx = tid; idx < 16 * 512; idx += 256) { int r = idx >> 9, c = idx & 511; hls[r][c] = hin[(size_t)(b0 + r) * 512 + c]; }
    __syncthreads();
    const int b = b0 + bl;
    const us* grow = gx + ((size_t)lrow * NB + b) * G;
    float ai = bf2f(grow[j]), af = bf2f(grow[512 + j]), ag = bf2f(grow[1024 + j]), ao = bf2f(grow[1536 + j]);
    const float* wi = Whh + (size_t)j * 512;
    const float* wf = Whh + (size_t)(512 + j) * 512;
    const float* wg = Whh + (size_t)(1024 + j) * 512;
    const float* wo = Whh + (size_t)(1536 + j) * 512;
    for (int k = 0; k < 512; k += 4) {
        float4 h4 = *(float4*)&hls[bl][k];
        float4 a = *(const float4*)&wi[k]; ai += a.x * h4.x + a.y * h4.y + a.z * h4.z + a.w * h4.w;
        float4 f = *(const float4*)&wf[k]; af += f.x * h4.x + f.y * h4.y + f.z * h4.z + f.w * h4.w;
        float4 g = *(const float4*)&wg[k]; ag += g.x * h4.x + g.y * h4.y + g.z * h4.z + g.w * h4.w;
        float4 o = *(const float4*)&wo[k]; ao += o.x * h4.x + o.y * h4.y + o.z * h4.z + o.w * h4.w;
    }
    const int ci = b * 512 + j;
    float cn = sigm(af) * cst[ci] + sigm(ai) * tanh_(ag);
    float hn = sigm(ao) * tanh_(cn);
    cst[ci] = cn;
    hout[ci] = hn;
    size_t hso = ((size_t)lrow * NB + b) * 1024 + dir * 512 + j;
    hs[hso] = hn;
    hs_bf[hso] = f2bf(hn);
}

// ---------------- decoder LSTM cell, fp32. grid (16 jtiles, 8 btiles), block 256 = 8b x 32j ----------------
__global__ __launch_bounds__(256) void dec_cell(const us* __restrict__ gemb, const float* __restrict__ Wcomb,
                                                const float* __restrict__ oin, const float* __restrict__ hin,
                                                float* __restrict__ hout, float* __restrict__ cst,
                                                us* __restrict__ hdec_bf, int t) {
    __shared__ float uls[8][1028];
    const int tid = threadIdx.x;
    const int bl = tid & 7, jl = tid >> 3;
    const int b0 = blockIdx.y * 8;
    const int j = blockIdx.x * 32 + jl;
    for (int idx = tid; idx < 8 * 1024; idx += 256) {
        int r = idx >> 10, c = idx & 1023;
        uls[r][c] = (c < 512) ? oin[(size_t)(b0 + r) * 512 + c] : hin[(size_t)(b0 + r) * 512 + (c - 512)];
    }
    __syncthreads();
    const int b = b0 + bl;
    const us* grow = gemb + ((size_t)t * NB + b) * G;
    float ai = bf2f(grow[j]), af = bf2f(grow[512 + j]), ag = bf2f(grow[1024 + j]), ao = bf2f(grow[1536 + j]);
    const float* wi = Wcomb + (size_t)j * 1024;
    const float* wf = Wcomb + (size_t)(512 + j) * 1024;
    const float* wg = Wcomb + (size_t)(1024 + j) * 1024;
    const float* wo = Wcomb + (size_t)(1536 + j) * 1024;
    for (int k = 0; k < 1024; k += 4) {
        float4 h4 = *(float4*)&uls[bl][k];
        float4 a = *(const float4*)&wi[k]; ai += a.x * h4.x + a.y * h4.y + a.z * h4.z + a.w * h4.w;
        float4 f = *(const float4*)&wf[k]; af += f.x * h4.x + f.y * h4.y + f.z * h4.z + f.w * h4.w;
        float4 g = *(const float4*)&wg[k]; ag += g.x * h4.x + g.y * h4.y + g.z * h4.z + g.w * h4.w;
        float4 o = *(const float4*)&wo[k]; ao += o.x * h4.x + o.y * h4.y + o.z * h4.z + o.w * h4.w;
    }
    const int ci = b * 512 + j;
    float cn = sigm(af) * cst[ci] + sigm(ai) * tanh_(ag);
    float hn = sigm(ao) * tanh_(cn);
    cst[ci] = cn;
    hout[ci] = hn;
    hdec_bf[((size_t)t * NB + b) * 512 + j] = f2bf(hn);
}

// ---------------- small-M fp32 GEMM: out[b][n] = act(dot(W[n], [U1[b];U2[b]]) + bias[n]) ----------------
// grid (N/32, 8 btiles), block 256 = 8b x 32j; dynamic LDS = 8*(K+4) floats
template <int ACT>
__global__ __launch_bounds__(256) void small_gemm(const float* __restrict__ U1, int K1,
                                                  const float* __restrict__ U2, int K2,
                                                  const float* __restrict__ W, int ldw,
                                                  const float* __restrict__ bias,
                                                  float* __restrict__ out, int ldo) {
    extern __shared__ float uls[];
    const int K = K1 + K2;
    const int stride = K + 4;
    const int tid = threadIdx.x;
    for (int r = 0; r < 8; r++) {
        int gb = blockIdx.y * 8 + r;
        for (int c = tid; c < K; c += 256) {
            float v = (c < K1) ? U1[(size_t)gb * K1 + c] : U2[(size_t)gb * K2 + (c - K1)];
            uls[r * stride + c] = v;
        }
    }
    __syncthreads();
    const int bl = tid & 7, jl = tid >> 3;
    const int b = blockIdx.y * 8 + bl;
    const int n = blockIdx.x * 32 + jl;
    const float* wr = W + (size_t)n * ldw;
    float acc = 0.f;
    for (int k = 0; k < K; k += 4) {
        float4 u = *(float4*)&uls[bl * stride + k];
        float4 wv = *(const float4*)&wr[k];
        acc += u.x * wv.x + u.y * wv.y + u.z * wv.z + u.w * wv.w;
    }
    if (bias) acc += bias[n];
    if (ACT == 1) acc = tanh_(acc);
    out[(size_t)b * ldo + n] = acc;
}

// ---------------- attention: scores/softmax/context per batch. grid 64, block 256 ----------------
__global__ __launch_bounds__(256) void dec_attn(const float* __restrict__ qbuf, const us* __restrict__ hsproj,
                                                const float* __restrict__ hs, const float* __restrict__ vat,
                                                float* __restrict__ catt) {
    const int b = blockIdx.x;
    const int tid = threadIdx.x;
    const int w = tid >> 6, l = tid & 63;
    __shared__ float sc[48];
    __shared__ float ps[48];
    float qv[16], vv[16];
#pragma unroll
    for (int i = 0; i < 16; i++) { qv[i] = qbuf[(size_t)b * 1024 + l * 16 + i]; vv[i] = vat[l * 16 + i]; }
    for (int li = w * 12; li < w * 12 + 12; ++li) {
        const us* hp = hsproj + ((size_t)li * NB + b) * 1024 + l * 16;
        float p = 0.f;
#pragma unroll
        for (int i = 0; i < 16; i++) p += vv[i] * tanh_(bf2f(hp[i]) + qv[i]);
#pragma unroll
        for (int m = 1; m < 64; m <<= 1) p += __shfl_xor(p, m);
        if (l == 0) sc[li] = p;
    }
    __syncthreads();
    if (w == 0) {
        float x = (l < 48) ? sc[l] : -1e30f;
        float mx = x;
#pragma unroll
        for (int m = 1; m < 64; m <<= 1) mx = fmaxf(mx, __shfl_xor(mx, m));
        float e = (l < 48) ? __expf(x - mx) : 0.f;
        float s = e;
#pragma unroll
        for (int m = 1; m < 64; m <<= 1) s += __shfl_xor(s, m);
        if (l < 48) ps[l] = e / s;
    }
    __syncthreads();
    float a0 = 0, a1 = 0, a2 = 0, a3 = 0;
    for (int li = 0; li < 48; ++li) {
        float p = ps[li];
        float4 hv = *(const float4*)(hs + ((size_t)li * NB + b) * 1024 + tid * 4);
        a0 += p * hv.x; a1 += p * hv.y; a2 += p * hv.z; a3 += p * hv.w;
    }
    float4 r; r.x = a0; r.y = a1; r.z = a2; r.w = a3;
    *(float4*)(catt + (size_t)b * 1024 + tid * 4) = r;
}

// ---------------- target logit: one wave per (t,b) row ----------------
__global__ __launch_bounds__(256) void tgt_kernel(const us* __restrict__ hdec_bf, const us* __restrict__ woutbf,
                                                  const float* __restrict__ out_b, const int* __restrict__ ts,
                                                  float* __restrict__ tgt) {
    int wid = blockIdx.x * 4 + (threadIdx.x >> 6);
    int l = threadIdx.x & 63;
    int t = wid >> 6, b = wid & 63;
    int tg = ts[(t + 1) * NB + b];
    const us* hr = hdec_bf + (size_t)wid * 512 + l * 8;
    const us* wr = woutbf + (size_t)tg * 512 + l * 8;
    float acc = 0.f;
#pragma unroll
    for (int i = 0; i < 8; i++) acc += bf2f(hr[i]) * bf2f(wr[i]);
#pragma unroll
    for (int m = 1; m < 64; m <<= 1) acc += __shfl_xor(acc, m);
    if (l == 0) tgt[wid] = acc + out_b[tg];
}

// ---------------- merge stats -> nll, masked mean accumulation ----------------
__global__ __launch_bounds__(256) void stats_reduce(const float* __restrict__ stats, const float* __restrict__ tgt,
                                                    const int* __restrict__ ts, float* __restrict__ sums) {
    int r = blockIdx.x * 256 + threadIdx.x;
    float nll = 0.f, mk = 0.f;
    if (r < MDEC) {
        float M = -1e30f, S = 0.f;
        for (int cb = 0; cb < NCB; ++cb) {
            float m = stats[((size_t)cb * MDEC + r) * 2];
            float s = stats[((size_t)cb * MDEC + r) * 2 + 1];
            if (m > M) { S = S * __expf(M - m) + s; M = m; }
            else { S += s * __expf(m - M); }
        }
        float logZ = M + __logf(S);
        int t = r >> 6, b = r & 63;
        int tg = ts[(t + 1) * NB + b];
        mk = (tg != 0) ? 1.f : 0.f;
        nll = (logZ - tgt[r]) * mk;
    }
#pragma unroll
    for (int m = 1; m < 64; m <<= 1) { nll += __shfl_xor(nll, m); mk += __shfl_xor(mk, m); }
    if ((threadIdx.x & 63) == 0) { atomicAdd(&sums[0], nll); atomicAdd(&sums[1], mk); }
}

__global__ void final_div(const float* __restrict__ sums, float* __restrict__ out) { out[0] = sums[0] / sums[1]; }

// ==================== host ====================
extern "C" void kernel_launch(void* const* d_in, const int* in_sizes, int n_in,
                              void* d_out, int out_size, void* d_ws, size_t ws_size,
                              hipStream_t stream) {
    const int* xs = (const int*)d_in[0];
    const int* ts = (const int*)d_in[1];
    const float* src_emb = (const float*)d_in[2];
    const float* tgt_emb = (const float*)d_in[3];
    const float* encf_Wih = (const float*)d_in[4];
    const float* encf_Whh = (const float*)d_in[5];
    const float* encf_bih = (const float*)d_in[6];
    const float* encf_bhh = (const float*)d_in[7];
    const float* encb_Wih = (const float*)d_in[8];
    const float* encb_Whh = (const float*)d_in[9];
    const float* encb_bih = (const float*)d_in[10];
    const float* encb_bhh = (const float*)d_in[11];
    const float* dec_Wih = (const float*)d_in[12];
    const float* dec_Whh = (const float*)d_in[13];
    const float* dec_bih = (const float*)d_in[14];
    const float* dec_bhh = (const float*)d_in[15];
    const float* attn_W = (const float*)d_in[16];
    const float* attn_v = (const float*)d_in[17];
    const float* lin_W = (const float*)d_in[18];
    const float* lin_b = (const float*)d_in[19];
    const float* out_W = (const float*)d_in[20];
    const float* out_b = (const float*)d_in[21];

    char* p = (char*)d_ws;
    auto alloc = [&](size_t bytes) { void* r = (void*)p; p += (bytes + 255) & ~(size_t)255; return r; };

    // zero zone (contiguous; each chunk is 256B-multiple)
    float* hf0 = (float*)alloc(NB * 512 * 4);
    float* hb0 = (float*)alloc(NB * 512 * 4);
    float* cf = (float*)alloc(NB * 512 * 4);
    float* cb = (float*)alloc(NB * 512 * 4);
    float* hd0 = (float*)alloc(NB * 512 * 4);
    float* cd = (float*)alloc(NB * 512 * 4);
    float* od = (float*)alloc(NB * 512 * 4);
    float* sums = (float*)alloc(2 * 4);
    const int ZN = 7 * NB * 512 + 64;

    float* hf1 = (float*)alloc(NB * 512 * 4);
    float* hb1 = (float*)alloc(NB * 512 * 4);
    float* hd1 = (float*)alloc(NB * 512 * 4);
    float* wcomb = (float*)alloc((size_t)G * 1024 * 4);
    float* hs = (float*)alloc((size_t)MENC * 1024 * 4);
    float* qbuf = (float*)alloc((size_t)NB * 1024 * 4);
    float* catt = (float*)alloc((size_t)NB * 1024 * 4);
    float* stats = (float*)alloc((size_t)NCB * MDEC * 2 * 4);
    float* tgtl = (float*)alloc((size_t)MDEC * 4);

    us* embs_bf = (us*)alloc((size_t)MENC * E * 2);
    us* tembs_bf = (us*)alloc((size_t)MDEC * E * 2);
    us* wfih_bf = (us*)alloc((size_t)G * 512 * 2);
    us* wbih_bf = (us*)alloc((size_t)G * 512 * 2);
    us* wdE_bf = (us*)alloc((size_t)G * 512 * 2);
    us* wk_bf = (us*)alloc((size_t)1024 * 1024 * 2);
    us* wout_bf = (us*)alloc((size_t)V * 512 * 2);
    us* gxf_bf = (us*)alloc((size_t)MENC * G * 2);
    us* gxb_bf = (us*)alloc((size_t)MENC * G * 2);
    us* gemb_bf = (us*)alloc((size_t)MDEC * G * 2);
    us* hs_bf = (us*)alloc((size_t)MENC * 1024 * 2);
    us* hsproj_bf = (us*)alloc((size_t)MENC * 1024 * 2);
    us* hdec_bf = (us*)alloc((size_t)MDEC * 512 * 2);

    // init states + sums
    zero_k<<<dim3((ZN + 255) / 256), 256, 0, stream>>>(hf0, ZN);

    // weight conversions
    conv_bf16<<<dim3((G * 512 + 255) / 256), 256, 0, stream>>>(encf_Wih, 512, 0, wfih_bf, G, 512);
    conv_bf16<<<dim3((G * 512 + 255) / 256), 256, 0, stream>>>(encb_Wih, 512, 0, wbih_bf, G, 512);
    conv_bf16<<<dim3((G * 512 + 255) / 256), 256, 0, stream>>>(dec_Wih, 1024, 0, wdE_bf, G, 512);
    conv_bf16<<<dim3((1024 * 1024 + 255) / 256), 256, 0, stream>>>(attn_W, 1536, 512, wk_bf, 1024, 1024);
    conv_bf16<<<dim3((V * 512 + 255) / 256), 256, 0, stream>>>(out_W, 512, 0, wout_bf, V, 512);
    pack_wcomb<<<dim3(G * 1024 / 256), 256, 0, stream>>>(dec_Wih, dec_Whh, wcomb);

    // embedding gathers
    gather_bf16<<<dim3(MENC), 256, 0, stream>>>(xs, src_emb, embs_bf);
    gather_bf16<<<dim3(MDEC), 256, 0, stream>>>(ts, tgt_emb, tembs_bf);

    // input-side gate preactivations (batched over all timesteps)
    gemm16<1><<<dim3(G / 64, MENC / 64), 256, 0, stream>>>(embs_bf, 512, wfih_bf, 512, encf_bih, encf_bhh, gxf_bf, G, 512, 0);
    gemm16<1><<<dim3(G / 64, MENC / 64), 256, 0, stream>>>(embs_bf, 512, wbih_bf, 512, encb_bih, encb_bhh, gxb_bf, G, 512, 0);
    gemm16<1><<<dim3(G / 64, MDEC / 64), 256, 0, stream>>>(tembs_bf, 512, wdE_bf, 512, dec_bih, dec_bhh, gemb_bf, G, 512, 0);

    // encoder scan (both directions in one launch per step)
    for (int s = 0; s < LS; ++s) {
        const float* hinf = (s & 1) ? hf1 : hf0; float* houtf = (s & 1) ? hf0 : hf1;
        const float* hinb = (s & 1) ? hb1 : hb0; float* houtb = (s & 1) ? hb0 : hb1;
        enc_step<<<dim3(32, 4, 2), 256, 0, stream>>>(gxf_bf, gxb_bf, encf_Whh, encb_Whh,
                                                     hinf, hinb, houtf, houtb, cf, cb, hs, hs_bf, s);
    }

    // hs_proj = hs @ Wk^T
    gemm16<1><<<dim3(1024 / 64, MENC / 64), 256, 0, stream>>>(hs_bf, 1024, wk_bf, 1024, nullptr, nullptr, hsproj_bf, 1024, 1024, 0);

    // decoder scan
    for (int t = 0; t < TD; ++t) {
        const float* hin = (t & 1) ? hd1 : hd0; float* hout = (t & 1) ? hd0 : hd1;
        dec_cell<<<dim3(16, 8), 256, 0, stream>>>(gemb_bf, wcomb, od, hin, hout, cd, hdec_bf, t);
        if (t < TD - 1) {
            small_gemm<0><<<dim3(32, 8), 256, (512 + 4) * 8 * 4, stream>>>(hout, 512, nullptr, 0, attn_W, 1536, nullptr, qbuf, 1024);
            dec_attn<<<dim3(NB), 256, 0, stream>>>(qbuf, hsproj_bf, hs, attn_v, catt);
            small_gemm<1><<<dim3(16, 8), 256, (1536 + 4) * 8 * 4, stream>>>(catt, 1024, hout, 512, lin_W, 1536, lin_b, od, 512);
        }
    }

    // logits GEMM with fused per-block logsumexp stats
    gemm16<2><<<dim3(NCB, MDEC / 64), 256, 0, stream>>>(hdec_bf, 512, wout_bf, 512, out_b, nullptr, stats, 0, 512, MDEC);

    // target logits, merge, final scalar
    tgt_kernel<<<dim3(MDEC / 4), 256, 0, stream>>>(hdec_bf, wout_bf, out_b, ts, tgtl);
    stats_reduce<<<dim3((MDEC + 255) / 256), 256, 0, stream>>>(stats, tgtl, ts, sums);
    final_div<<<dim3(1), 1, 0, stream>>>(sums, (float*)d_out);
}